// Round 1
// baseline (655.575 us; speedup 1.0000x reference)
//
#include <hip/hip_runtime.h>
#include <hip/hip_bf16.h>
#include <math.h>

#define NN 8192
#define DD 512
#define INV_T 14.285714285714286f   // 1/0.07 ; also the logits_max (diagonal) value

typedef __attribute__((ext_vector_type(8))) short s16x8;  // 8 bf16 = 4 VGPRs
typedef __attribute__((ext_vector_type(4))) float f32x4;

__device__ __forceinline__ unsigned short f32_to_bf16(float f) {
  unsigned int u = __float_as_uint(f);
  u += 0x7FFFu + ((u >> 16) & 1u);   // round-to-nearest-even
  return (unsigned short)(u >> 16);
}

__device__ __forceinline__ void async16(const void* g, void* l) {
  // 16B-wide global->LDS DMA (guide §5: width 16 is the m93->m97 2x step)
  __builtin_amdgcn_global_load_lds((__attribute__((address_space(1))) void*)(void*)g,
                                   (__attribute__((address_space(3))) void*)l,
                                   16, 0, 0);
}

// ---------------- Kernel A: normalize rows, emit bf16 ----------------
__global__ __launch_bounds__(256) void normalize_kernel(const float* __restrict__ f,
                                                        unsigned short* __restrict__ fnb) {
  const int wave = threadIdx.x >> 6;
  const int lane = threadIdx.x & 63;
  const int row  = blockIdx.x * 4 + wave;
  const float* src = f + (size_t)row * DD + lane * 8;
  float4 v0 = *(const float4*)src;
  float4 v1 = *(const float4*)(src + 4);
  float ss = v0.x*v0.x + v0.y*v0.y + v0.z*v0.z + v0.w*v0.w
           + v1.x*v1.x + v1.y*v1.y + v1.z*v1.z + v1.w*v1.w;
  #pragma unroll
  for (int o = 32; o; o >>= 1) ss += __shfl_xor(ss, o);
  const float r = 1.0f / fmaxf(sqrtf(ss), 1e-8f);
  ushort4 a, b;
  a.x = f32_to_bf16(v0.x * r); a.y = f32_to_bf16(v0.y * r);
  a.z = f32_to_bf16(v0.z * r); a.w = f32_to_bf16(v0.w * r);
  b.x = f32_to_bf16(v1.x * r); b.y = f32_to_bf16(v1.y * r);
  b.z = f32_to_bf16(v1.z * r); b.w = f32_to_bf16(v1.w * r);
  unsigned short* dst = fnb + (size_t)row * DD + lane * 8;
  *(ushort4*)dst = a;
  *(ushort4*)(dst + 4) = b;
}

// ---------------- Kernel B: fused upper-tri sim tile + epilogue ----------------
// 128x128 tile per block, 4 waves each 64x64 (4x4 of 16x16x32 bf16 MFMA), BK=32.
__global__ __launch_bounds__(256) void fused_kernel(const unsigned short* __restrict__ fnb,
                                                    const int* __restrict__ posm,
                                                    const int* __restrict__ negm,
                                                    float* __restrict__ Spos,
                                                    float* __restrict__ Sneg,
                                                    float* __restrict__ Pcnt) {
  const int bi = blockIdx.y;
  const int bj = blockIdx.x;
  if (bj < bi) return;                 // upper-triangular blocks only
  const int I = bi * 128;
  const int J = bj * 128;

  const int tid  = threadIdx.x;
  const int wave = tid >> 6;
  const int lane = tid & 63;
  const int wm = wave >> 1;            // 0..1 row half
  const int wn = wave & 1;             // 0..1 col half
  const int q   = lane >> 4;           // 0..3
  const int c16 = lane & 15;           // 0..15

  __shared__ alignas(16) unsigned short lA[128 * 32];
  __shared__ alignas(16) unsigned short lB[128 * 32];

  f32x4 acc[4][4];
  const f32x4 z4 = {0.f, 0.f, 0.f, 0.f};
  #pragma unroll
  for (int mt = 0; mt < 4; ++mt)
    #pragma unroll
    for (int nt = 0; nt < 4; ++nt) acc[mt][nt] = z4;

  for (int kk = 0; kk < DD / 32; ++kk) {
    const int k0 = kk * 32;
    #pragma unroll
    for (int c = 0; c < 2; ++c) {
      const int fidx = tid + c * 256;        // 0..511 16B-chunks
      const int row  = fidx >> 2;
      const int ke   = (fidx & 3) * 8;
      async16(fnb + (size_t)(I + row) * DD + k0 + ke, (char*)lA + fidx * 16);
      async16(fnb + (size_t)(J + row) * DD + k0 + ke, (char*)lB + fidx * 16);
    }
    __syncthreads();   // compiler drains vmcnt before barrier -> LDS data ready

    s16x8 aF[4], bF[4];
    #pragma unroll
    for (int t = 0; t < 4; ++t) {
      const int arow = wm * 64 + t * 16 + c16;
      aF[t] = *(const s16x8*)((const char*)lA + arow * 64 + q * 16);
      const int brow = wn * 64 + t * 16 + c16;
      bF[t] = *(const s16x8*)((const char*)lB + brow * 64 + q * 16);
    }
    #pragma unroll
    for (int mt = 0; mt < 4; ++mt)
      #pragma unroll
      for (int nt = 0; nt < 4; ++nt)
        acc[mt][nt] = __builtin_amdgcn_mfma_f32_16x16x32_bf16(aF[mt], bF[nt], acc[mt][nt], 0, 0, 0);
    __syncthreads();   // protect LDS from next iteration's staging
  }

  // ---- epilogue: e = exp(sim - M); accumulate row sums (direct) and col sums (transposed) ----
  float tsp[4] = {0,0,0,0}, tsn[4] = {0,0,0,0}, tpc[4] = {0,0,0,0};
  const bool offdiag = (bi != bj);

  #pragma unroll
  for (int mt = 0; mt < 4; ++mt) {
    float dsp[4] = {0,0,0,0}, dsn[4] = {0,0,0,0}, dpc[4] = {0,0,0,0};
    const int rbase = I + wm * 64 + mt * 16 + q * 4;   // + r
    #pragma unroll
    for (int nt = 0; nt < 4; ++nt) {
      const int col = J + wn * 64 + nt * 16 + c16;
      float e[4];
      #pragma unroll
      for (int r = 0; r < 4; ++r)
        e[r] = __expf(acc[mt][nt][r] * INV_T - INV_T);
      #pragma unroll
      for (int r = 0; r < 4; ++r) {
        const int row = rbase + r;
        const int off = row * NN + col;     // < 2^31
        float pf = (float)posm[off];
        float nf = (float)negm[off];
        if (row == col) { pf = 0.f; nf = 0.f; }   // self-contrast zero diagonal
        dsp[r] = fmaf(e[r], pf, dsp[r]);
        dsn[r] = fmaf(e[r], nf, dsn[r]);
        dpc[r] += pf;
      }
      if (offdiag) {  // sim(col,row) == sim(row,col): accumulate for rows in J-range
        const int toff = col * NN + rbase;  // 16B-aligned
        const int4 pT = *(const int4*)(posm + toff);
        const int4 nT = *(const int4*)(negm + toff);
        tsp[nt] += e[0]*(float)pT.x + e[1]*(float)pT.y + e[2]*(float)pT.z + e[3]*(float)pT.w;
        tsn[nt] += e[0]*(float)nT.x + e[1]*(float)nT.y + e[2]*(float)nT.z + e[3]*(float)nT.w;
        tpc[nt] += (float)(pT.x + pT.y + pT.z + pT.w);
      }
    }
    // reduce over the 16 lanes holding this row's columns
    #pragma unroll
    for (int r = 0; r < 4; ++r) {
      float a = dsp[r], b = dsn[r], p = dpc[r];
      #pragma unroll
      for (int o = 1; o <= 8; o <<= 1) {
        a += __shfl_xor(a, o);
        b += __shfl_xor(b, o);
        p += __shfl_xor(p, o);
      }
      if (c16 == 0) {
        atomicAdd(&Spos[rbase + r], a);
        atomicAdd(&Sneg[rbase + r], b);
        atomicAdd(&Pcnt[rbase + r], p);
      }
    }
  }

  if (offdiag) {
    #pragma unroll
    for (int nt = 0; nt < 4; ++nt) {
      float a = tsp[nt], b = tsn[nt], p = tpc[nt];
      a += __shfl_xor(a, 16); a += __shfl_xor(a, 32);
      b += __shfl_xor(b, 16); b += __shfl_xor(b, 32);
      p += __shfl_xor(p, 16); p += __shfl_xor(p, 32);
      if (q == 0) {
        const int col = J + wn * 64 + nt * 16 + c16;
        atomicAdd(&Spos[col], a);
        atomicAdd(&Sneg[col], b);
        atomicAdd(&Pcnt[col], p);
      }
    }
  }
}

// ---------------- Kernel C: finalize ----------------
__global__ __launch_bounds__(256) void finalize_kernel(const float* __restrict__ Spos,
                                                       const float* __restrict__ Sneg,
                                                       const float* __restrict__ Pcnt,
                                                       float* __restrict__ out) {
  float local = 0.f;
  for (int i = threadIdx.x; i < NN; i += 256) {
    const float sp = Spos[i], sn = Sneg[i], pc = Pcnt[i];
    const float card = (pc == 0.f) ? 1.f : pc;
    // loss_i = -(sp - log(sn)*pc)/card
    local += (logf(sn) * pc - sp) / card;
  }
  #pragma unroll
  for (int o = 32; o; o >>= 1) local += __shfl_xor(local, o);
  __shared__ float red[4];
  if ((threadIdx.x & 63) == 0) red[threadIdx.x >> 6] = local;
  __syncthreads();
  if (threadIdx.x == 0)
    out[0] = (red[0] + red[1] + red[2] + red[3]) * (1.0f / (float)NN);
}

extern "C" void kernel_launch(void* const* d_in, const int* in_sizes, int n_in,
                              void* d_out, int out_size, void* d_ws, size_t ws_size,
                              hipStream_t stream) {
  const float* feat = (const float*)d_in[0];
  const int* posm   = (const int*)d_in[1];
  const int* negm   = (const int*)d_in[2];
  float* out = (float*)d_out;

  unsigned short* fnb = (unsigned short*)d_ws;                 // 8192*512 bf16 = 8 MB
  float* Spos = (float*)((char*)d_ws + (size_t)NN * DD * 2);   // +8 MB
  float* Sneg = Spos + NN;
  float* Pcnt = Sneg + NN;

  hipMemsetAsync(Spos, 0, 3 * NN * sizeof(float), stream);
  normalize_kernel<<<NN / 4, 256, 0, stream>>>(feat, fnb);
  dim3 grid(64, 64);
  fused_kernel<<<grid, 256, 0, stream>>>(fnb, posm, negm, Spos, Sneg, Pcnt);
  finalize_kernel<<<1, 256, 0, stream>>>(Spos, Sneg, Pcnt, out);
}